// Round 8
// baseline (645.568 us; speedup 1.0000x reference)
//
#include <hip/hip_runtime.h>
#include <hip/hip_bf16.h>
#include <cstdint>
#include <cstddef>

#define M_DIM 8192
#define K_DIM 4096
#define N_DIM 4096
#define EPS 1e-5f

typedef __bf16 bf16x8 __attribute__((ext_vector_type(8)));
typedef unsigned short u16x8 __attribute__((ext_vector_type(8)));
typedef float f32x4 __attribute__((ext_vector_type(4)));

// ---------- helpers ----------

__device__ __forceinline__ unsigned short f2bf(float f) {
  unsigned int u = __builtin_bit_cast(unsigned int, f);
  u += 0x7fffu + ((u >> 16) & 1u);   // round-to-nearest-even
  return (unsigned short)(u >> 16);
}

// GELU(tanh-approx)+ReLU via identity 0.5y(1+tanh(w)) = y*sigmoid(2w):
// ge = y / (1 + exp2(-c2*z)), z = y + 0.044715 y^3, c2 = 2*0.7978845608*log2(e)
__device__ __forceinline__ float fused_epilogue(float acc, float inv, float shift) {
  float y = fmaf(acc, inv, shift);
  float y2 = y * y;
  float z = fmaf(0.044715f * y2, y, y);
  float e = __builtin_amdgcn_exp2f(-2.3022081f * z);
  float ge = y * __builtin_amdgcn_rcpf(1.0f + e);
  return fmaxf(ge, 0.0f);
}

__device__ __forceinline__ void gload_lds16(const void* gsrc, void* ldst) {
  __builtin_amdgcn_global_load_lds(
      (const __attribute__((address_space(1))) void*)gsrc,
      (__attribute__((address_space(3))) void*)ldst,
      16, 0, 0);
}

// ---------- pre-pass: fp32 -> bf16 conversions ----------

__global__ __launch_bounds__(256) void cvt_x_kernel(const float* __restrict__ x,
                                                    unsigned short* __restrict__ xb) {
  size_t i = ((size_t)blockIdx.x * 256 + threadIdx.x) * 8;
  float4 a = *reinterpret_cast<const float4*>(x + i);
  float4 b = *reinterpret_cast<const float4*>(x + i + 4);
  u16x8 o;
  o[0] = f2bf(a.x); o[1] = f2bf(a.y); o[2] = f2bf(a.z); o[3] = f2bf(a.w);
  o[4] = f2bf(b.x); o[5] = f2bf(b.y); o[6] = f2bf(b.z); o[7] = f2bf(b.w);
  *reinterpret_cast<u16x8*>(xb + i) = o;
}

// W [K][N] fp32 -> Wt [N][K] bf16 (transpose + convert)
__global__ __launch_bounds__(256) void cvt_w_transpose(const float* __restrict__ W,
                                                       unsigned short* __restrict__ Wt) {
  __shared__ float tile[32][33];
  const int tx = threadIdx.x & 31;
  const int tg = threadIdx.x >> 5;
  const int n0 = blockIdx.x * 32;
  const int k0 = blockIdx.y * 32;
#pragma unroll
  for (int j = 0; j < 4; ++j) {
    int k = tg * 4 + j;
    tile[k][tx] = W[(size_t)(k0 + k) * N_DIM + n0 + tx];
  }
  __syncthreads();
#pragma unroll
  for (int j = 0; j < 4; ++j) {
    int n = tg * 4 + j;
    Wt[(size_t)(n0 + n) * K_DIM + k0 + tx] = f2bf(tile[tx][n]);
  }
}

// ---------- main GEMM: 256x256 tile, BK=64, 8 waves ----------
// A: DIRECT global->VGPR fragment loads (no LDS), register time-shared:
//    A(t+1) kh0 issued after kh0(t) MFMAs free the regs (1-tile latency slack).
// B: gload_lds into a 3-slot LDS ring (32 KiB/slot, 96 KiB total), staged 2
//    tiles ahead, R4-proven col8^(row&7) swizzle. ONE barrier per K-tile
//    (ring distance 3 > staging distance 2 proves no overwrite race).
// vmcnt ledger/wave: steady outstanding = B(t+2)x4 + A(t)kh0 x8 + A(t)kh1 x8;
// vmcnt(12) before each k-half's MFMAs; tails 8/8 then 8/0; never 0 mid-loop.

#define STGB(h, j, SW, T)                                                          \
  gload_lds16(bS + (size_t)((h)*128 + 64*(j)) * K_DIM + (size_t)((T) + 2) * 64,    \
              &lds[(SW)*16384 + (h)*8192 + (wave + 8*(j)) * 512])

#define LDS_FRAG(off) __builtin_bit_cast(bf16x8, *(const u16x8*)&lds[(off)])

#define LDA(BUF, T, KH)                                                            \
  _Pragma("unroll") for (int mi = 0; mi < 8; ++mi)                                 \
    BUF[mi] = __builtin_bit_cast(bf16x8, *reinterpret_cast<const u16x8*>(          \
        aG + (size_t)mi * (16 * K_DIM) + (size_t)(T) * 64 + (KH) * 32))

#define MFMA_HALF(AK, BV)                                                          \
  _Pragma("unroll") for (int mi = 0; mi < 8; ++mi)                                 \
  _Pragma("unroll") for (int ni = 0; ni < 4; ++ni)                                 \
    acc[mi][ni] = __builtin_amdgcn_mfma_f32_16x16x32_bf16(AK[mi], BV[ni],          \
                                                          acc[mi][ni], 0, 0, 0)

#define VMC(N)                                                                     \
  if ((N) == 12)     asm volatile("s_waitcnt vmcnt(12)" ::: "memory");             \
  else if ((N) == 8) asm volatile("s_waitcnt vmcnt(8)"  ::: "memory");             \
  else               asm volatile("s_waitcnt vmcnt(0)"  ::: "memory")

#define KTILE(T, SR, SW, STB, VMA, VMB, ANX, BAR) do {                             \
  if (STB) { STGB(0,0,SW,T); STGB(0,1,SW,T);                                       \
             STGB(1,0,SW,T); STGB(1,1,SW,T); }                                     \
  asm volatile("" ::: "memory");                                                   \
  bf16x8 b0[4], b1[4];                                                             \
  _Pragma("unroll") for (int ni = 0; ni < 4; ++ni)                                 \
    b0[ni] = LDS_FRAG((SR)*16384 + bro + ni * 1024 + xk0);                         \
  VMC(VMA);                                                                        \
  __builtin_amdgcn_s_setprio(1);                                                   \
  MFMA_HALF(aK0, b0);                                                              \
  __builtin_amdgcn_s_setprio(0);                                                   \
  _Pragma("unroll") for (int ni = 0; ni < 4; ++ni)                                 \
    b1[ni] = LDS_FRAG((SR)*16384 + bro + ni * 1024 + xk1);                         \
  asm volatile("" ::: "memory");                                                   \
  if (ANX) { LDA(aK0, (T) + 1, 0); }       /* refill kh0 regs for next tile */     \
  asm volatile("" ::: "memory");                                                   \
  VMC(VMB);                                                                        \
  __builtin_amdgcn_s_setprio(1);                                                   \
  MFMA_HALF(aK1, b1);                                                              \
  __builtin_amdgcn_s_setprio(0);                                                   \
  asm volatile("" ::: "memory");                                                   \
  if (ANX) { LDA(aK1, (T) + 1, 1); }       /* refill kh1 regs for next tile */     \
  asm volatile("" ::: "memory");                                                   \
  if (BAR) {                                                                       \
    asm volatile("s_waitcnt lgkmcnt(0)" ::: "memory");                             \
    __builtin_amdgcn_s_barrier();                                                  \
  }                                                                                \
} while (0)

__global__ __launch_bounds__(512, 2) void gemm_bf16_fused(
    const unsigned short* __restrict__ A,
    const unsigned short* __restrict__ Bt,
    const float* __restrict__ gam, const float* __restrict__ bet,
    const float* __restrict__ mu, const float* __restrict__ var,
    float* __restrict__ C) {
  __shared__ __align__(16) unsigned short lds[49152];  // 96 KiB: 3 B-slots

  const int tid = threadIdx.x;
  const int wave = tid >> 6;
  const int lane = tid & 63;
  const int l15 = lane & 15, l4 = lane >> 4;
  const int wr = wave >> 2, wc = wave & 3;   // 2M x 4N wave grid; per-wave 128x64

  // XCD-aware swizzle: 512 blocks, 512 % 8 == 0 -> bijective
  const int bid = (int)blockIdx.x;
  const int swz = (bid & 7) * 64 + (bid >> 3);
  const int bx = swz & 15;                   // 16 N-tiles
  const int by = swz >> 4;                   // 32 M-tiles
  const size_t bm = (size_t)by * 256;
  const size_t bn = (size_t)bx * 256;

  // B stage source (pre-swizzled global per lane; LDS dest linear) — R4-proven
  const int lr = lane >> 3, lc = lane & 7;
  const unsigned short* bS = Bt + (bn + (size_t)(wave * 8 + lr)) * K_DIM + (lc ^ lr) * 8;

  // B ds_read offsets (u16 units); col8' = col8 ^ (row&7), row&7 == l15&7
  const int xk0 = ((l4)     ^ (l15 & 7)) * 8;
  const int xk1 = ((l4 | 4) ^ (l15 & 7)) * 8;
  const int bro = (wc >> 1) * 8192 + (wc & 1) * 4096 + l15 * 64;

  // A direct-load base: lane (l15,l4) reads row (..+mi*16+l15), k = t*64+kh*32+l4*8
  const unsigned short* aG = A + (bm + (size_t)(wr * 128 + l15)) * K_DIM + l4 * 8;

  f32x4 acc[8][4] = {};
  bf16x8 aK0[8], aK1[8];

  // ---- prologue: B(0)->slot0, B(1)->slot1; A(0) both halves to regs ----
  STGB(0, 0, 0, -2); STGB(0, 1, 0, -2); STGB(1, 0, 0, -2); STGB(1, 1, 0, -2);
  asm volatile("" ::: "memory");
  STGB(0, 0, 1, -1); STGB(0, 1, 1, -1); STGB(1, 0, 1, -1); STGB(1, 1, 1, -1);
  asm volatile("" ::: "memory");
  LDA(aK0, 0, 0);
  asm volatile("" ::: "memory");
  LDA(aK1, 0, 1);
  asm volatile("s_waitcnt vmcnt(20)" ::: "memory");   // B(0) landed
  __builtin_amdgcn_s_barrier();

  // ---- main loop: 64 K-tiles; read slot t%3, write slot (t+2)%3 ----
  for (int t = 0; t < 60; t += 3) {
    KTILE(t,     0, 2, 1, 12, 12, 1, 1);
    KTILE(t + 1, 1, 0, 1, 12, 12, 1, 1);
    KTILE(t + 2, 2, 1, 1, 12, 12, 1, 1);
  }
  KTILE(60, 0, 2, 1, 12, 12, 1, 1);
  KTILE(61, 1, 0, 1, 12, 12, 1, 1);   // stages B(63) -> slot0
  KTILE(62, 2, 1, 0,  8,  8, 1, 1);   // no B stage; ledger shrinks
  KTILE(63, 0, 0, 0,  8,  0, 0, 0);   // final: full drain, no barrier

  // ---- epilogue: fused BN + GELU + ReLU ----
  const int row0 = (int)bm + wr * 128;
  const int col0 = (int)bn + wc * 64;
#pragma unroll
  for (int ni = 0; ni < 4; ++ni) {
    const int col = col0 + ni * 16 + l15;
    const float inv = rsqrtf(var[col] + EPS) * gam[col];
    const float shift = fmaf(-mu[col], inv, bet[col]);
#pragma unroll
    for (int mi = 0; mi < 8; ++mi) {
      const int r0 = row0 + mi * 16 + l4 * 4;
#pragma unroll
      for (int r = 0; r < 4; ++r)
        C[(size_t)(r0 + r) * N_DIM + col] = fused_epilogue(acc[mi][ni][r], inv, shift);
    }
  }
}

// ---------- fallback (only if ws too small): fp32 tiled GEMM ----------

__global__ __launch_bounds__(256) void gemm_f32_fallback(
    const float* __restrict__ A, const float* __restrict__ W,
    const float* __restrict__ gam, const float* __restrict__ bet,
    const float* __restrict__ mu, const float* __restrict__ var,
    float* __restrict__ C) {
  __shared__ float As[16][65];
  __shared__ float Bs[16][65];
  const int tid = threadIdx.x;
  const int tx = tid & 15, ty = tid >> 4;
  const int bn0 = blockIdx.x * 64, bm0 = blockIdx.y * 64;
  float acc[4][4] = {};
  for (int k0 = 0; k0 < K_DIM; k0 += 16) {
#pragma unroll
    for (int j = 0; j < 4; ++j)
      As[tid & 15][(tid >> 4) * 4 + j] =
          A[(size_t)(bm0 + (tid >> 4) * 4 + j) * K_DIM + k0 + (tid & 15)];
#pragma unroll
    for (int j = 0; j < 4; ++j)
      Bs[tid >> 4][(tid & 15) * 4 + j] =
          W[(size_t)(k0 + (tid >> 4)) * N_DIM + bn0 + (tid & 15) * 4 + j];
    __syncthreads();
#pragma unroll
    for (int kk = 0; kk < 16; ++kk) {
      float a_[4], b_[4];
#pragma unroll
      for (int i = 0; i < 4; ++i) a_[i] = As[kk][ty * 4 + i];
#pragma unroll
      for (int j = 0; j < 4; ++j) b_[j] = Bs[kk][tx * 4 + j];
#pragma unroll
      for (int i = 0; i < 4; ++i)
#pragma unroll
        for (int j = 0; j < 4; ++j)
          acc[i][j] = fmaf(a_[i], b_[j], acc[i][j]);
    }
    __syncthreads();
  }
#pragma unroll
  for (int j = 0; j < 4; ++j) {
    const int col = bn0 + tx * 4 + j;
    const float inv = rsqrtf(var[col] + EPS) * gam[col];
    const float shift = fmaf(-mu[col], inv, bet[col]);
#pragma unroll
    for (int i = 0; i < 4; ++i) {
      float y = fmaf(acc[i][j], inv, shift);
      float y2 = y * y;
      float z = fmaf(0.044715f * y2, y, y);
      float e = __builtin_amdgcn_exp2f(-2.3022081f * z);
      float ge = y * __builtin_amdgcn_rcpf(1.0f + e);
      C[(size_t)(bm0 + ty * 4 + i) * N_DIM + col] = fmaxf(ge, 0.0f);
    }
  }
}

// ---------- launch ----------

extern "C" void kernel_launch(void* const* d_in, const int* in_sizes, int n_in,
                              void* d_out, int out_size, void* d_ws, size_t ws_size,
                              hipStream_t stream) {
  const float* x  = (const float*)d_in[0];
  const float* w  = (const float*)d_in[1];
  const float* gg = (const float*)d_in[2];
  const float* bb = (const float*)d_in[3];
  const float* mu = (const float*)d_in[4];
  const float* vr = (const float*)d_in[5];
  float* out = (float*)d_out;

  const size_t xb_bytes = (size_t)M_DIM * K_DIM * 2;
  const size_t wt_bytes = (size_t)K_DIM * N_DIM * 2;

  if (ws_size >= xb_bytes + wt_bytes) {
    unsigned short* xb = (unsigned short*)d_ws;
    unsigned short* wt = xb + (size_t)M_DIM * K_DIM;
    cvt_x_kernel<<<dim3((M_DIM * (size_t)K_DIM) / 8 / 256), dim3(256), 0, stream>>>(x, xb);
    cvt_w_transpose<<<dim3(N_DIM / 32, K_DIM / 32), dim3(256), 0, stream>>>(w, wt);
    gemm_bf16_fused<<<dim3((M_DIM / 256) * (N_DIM / 256)), dim3(512), 0, stream>>>(
        xb, wt, gg, bb, mu, vr, out);
  } else {
    gemm_f32_fallback<<<dim3(N_DIM / 64, M_DIM / 64), dim3(256), 0, stream>>>(
        x, w, gg, bb, mu, vr, out);
  }
}

// Round 9
// 306.917 us; speedup vs baseline: 2.1034x; 2.1034x over previous
//
#include <hip/hip_runtime.h>
#include <hip/hip_bf16.h>
#include <cstdint>
#include <cstddef>

#define M_DIM 8192
#define K_DIM 4096
#define N_DIM 4096
#define EPS 1e-5f

typedef __bf16 bf16x8 __attribute__((ext_vector_type(8)));
typedef unsigned short u16x8 __attribute__((ext_vector_type(8)));
typedef float f32x4 __attribute__((ext_vector_type(4)));
typedef float f32x16 __attribute__((ext_vector_type(16)));

// ---------- helpers ----------

__device__ __forceinline__ unsigned short f2bf(float f) {
  unsigned int u = __builtin_bit_cast(unsigned int, f);
  u += 0x7fffu + ((u >> 16) & 1u);   // round-to-nearest-even
  return (unsigned short)(u >> 16);
}

// GELU(tanh-approx)+ReLU via identity 0.5y(1+tanh(w)) = y*sigmoid(2w):
// ge = y / (1 + exp2(-c2*z)), z = y + 0.044715 y^3, c2 = 2*0.7978845608*log2(e)
__device__ __forceinline__ float fused_epilogue(float acc, float inv, float shift) {
  float y = fmaf(acc, inv, shift);
  float y2 = y * y;
  float z = fmaf(0.044715f * y2, y, y);
  float e = __builtin_amdgcn_exp2f(-2.3022081f * z);
  float ge = y * __builtin_amdgcn_rcpf(1.0f + e);
  return fmaxf(ge, 0.0f);
}

__device__ __forceinline__ void gload_lds16(const void* gsrc, void* ldst) {
  __builtin_amdgcn_global_load_lds(
      (const __attribute__((address_space(1))) void*)gsrc,
      (__attribute__((address_space(3))) void*)ldst,
      16, 0, 0);
}

// ---------- pre-pass: fp32 -> bf16 conversions ----------

__global__ __launch_bounds__(256) void cvt_x_kernel(const float* __restrict__ x,
                                                    unsigned short* __restrict__ xb) {
  size_t i = ((size_t)blockIdx.x * 256 + threadIdx.x) * 8;
  float4 a = *reinterpret_cast<const float4*>(x + i);
  float4 b = *reinterpret_cast<const float4*>(x + i + 4);
  u16x8 o;
  o[0] = f2bf(a.x); o[1] = f2bf(a.y); o[2] = f2bf(a.z); o[3] = f2bf(a.w);
  o[4] = f2bf(b.x); o[5] = f2bf(b.y); o[6] = f2bf(b.z); o[7] = f2bf(b.w);
  *reinterpret_cast<u16x8*>(xb + i) = o;
}

// W [K][N] fp32 -> Wt [N][K] bf16 (transpose + convert)
__global__ __launch_bounds__(256) void cvt_w_transpose(const float* __restrict__ W,
                                                       unsigned short* __restrict__ Wt) {
  __shared__ float tile[32][33];
  const int tx = threadIdx.x & 31;
  const int tg = threadIdx.x >> 5;
  const int n0 = blockIdx.x * 32;
  const int k0 = blockIdx.y * 32;
#pragma unroll
  for (int j = 0; j < 4; ++j) {
    int k = tg * 4 + j;
    tile[k][tx] = W[(size_t)(k0 + k) * N_DIM + n0 + tx];
  }
  __syncthreads();
#pragma unroll
  for (int j = 0; j < 4; ++j) {
    int n = tg * 4 + j;
    Wt[(size_t)(n0 + n) * K_DIM + k0 + tx] = f2bf(tile[tx][n]);
  }
}

// ---------- main GEMM: 256x256 tile, BK=64, 8 waves, 2-barrier K-tile ----------
// R4's proven hazard structure/ledger, with MFMA shape 32x32x16 (HK/AITER/BLASLt
// shape): per wave 4mi x 2ni frags of 32x32, 4 k-steps of 16. Same LDS layout,
// swizzle, staging, parity ring, vmcnt(4) as R4.
//
// Per tile t (parity PAR):
//  - STG_A(t+1) -> parity 1-PAR A slots (dead since end-barrier(t-1)). [top]
//  - pre-mid reads: B kk01 (4), A kk01 (8), B kk23 (4); MFMA kk01 (16).
//  - mid: lgkmcnt(0)+barrier => B(t) fully in regs -> STG_B(t+2) safe.
//  - A kk23 reads (8, parity-PAR A slots untouched); MFMA kk23 (16).
//  - end: lgkmcnt(0); vmcnt(4) keeps B(t+2) in flight; barrier.

#define STG_A(h, j, PAR, T)                                                        \
  gload_lds16(aS + (size_t)((h)*128 + 64*(j)) * K_DIM + (size_t)((T) + 1) * 64,    \
              &lds[(2*(1-(PAR)) + (h)) * 8192 + (wave + 8*(j)) * 512])

#define STG_B(h, j, PAR, T)                                                        \
  gload_lds16(bS + (size_t)((h)*128 + 64*(j)) * K_DIM + (size_t)((T) + 2) * 64,    \
              &lds[32768 + (2*(PAR) + (h)) * 8192 + (wave + 8*(j)) * 512])

#define LDS_FRAG(off) __builtin_bit_cast(bf16x8, *(const u16x8*)&lds[(off)])

#define MFMA32(a, b, c) __builtin_amdgcn_mfma_f32_32x32x16_bf16(a, b, c, 0, 0, 0)

#define KTILE(T, PAR, STA, STB, VM) do {                                           \
  const int sa = (PAR) * 16384 + saW;                                              \
  const int sb = (PAR) * 16384 + sbW;                                              \
  if (STA) { STG_A(0,0,PAR,T); STG_A(0,1,PAR,T);                                   \
             STG_A(1,0,PAR,T); STG_A(1,1,PAR,T); }                                 \
  asm volatile("" ::: "memory");                                                   \
  bf16x8 b0[2][2], b1[2][2], a0[4][2], a1[4][2];                                   \
  /* pre-mid reads: B kk0/1, A kk0/1, B kk2/3 */                                   \
  _Pragma("unroll") for (int ni = 0; ni < 2; ++ni) {                               \
    b0[ni][0] = LDS_FRAG(sb + bro + ni * 2048 + xc0);                              \
    b0[ni][1] = LDS_FRAG(sb + bro + ni * 2048 + xc1);                              \
  }                                                                                \
  _Pragma("unroll") for (int mi = 0; mi < 4; ++mi) {                               \
    a0[mi][0] = LDS_FRAG(sa + aro + mi * 2048 + xc0);                              \
    a0[mi][1] = LDS_FRAG(sa + aro + mi * 2048 + xc1);                              \
  }                                                                                \
  _Pragma("unroll") for (int ni = 0; ni < 2; ++ni) {                               \
    b1[ni][0] = LDS_FRAG(sb + bro + ni * 2048 + xc2);                              \
    b1[ni][1] = LDS_FRAG(sb + bro + ni * 2048 + xc3);                              \
  }                                                                                \
  __builtin_amdgcn_s_setprio(1);                                                   \
  _Pragma("unroll") for (int q = 0; q < 2; ++q)                                    \
  _Pragma("unroll") for (int mi = 0; mi < 4; ++mi)                                 \
  _Pragma("unroll") for (int ni = 0; ni < 2; ++ni)                                 \
    acc[mi][ni] = MFMA32(a0[mi][q], b0[ni][q], acc[mi][ni]);                       \
  __builtin_amdgcn_s_setprio(0);                                                   \
  asm volatile("s_waitcnt lgkmcnt(0)" ::: "memory");                               \
  __builtin_amdgcn_s_barrier();           /* MID: B(t) fully consumed */           \
  if (STB) { STG_B(0,0,PAR,T); STG_B(0,1,PAR,T);                                   \
             STG_B(1,0,PAR,T); STG_B(1,1,PAR,T); }                                 \
  asm volatile("" ::: "memory");                                                   \
  _Pragma("unroll") for (int mi = 0; mi < 4; ++mi) {                               \
    a1[mi][0] = LDS_FRAG(sa + aro + mi * 2048 + xc2);                              \
    a1[mi][1] = LDS_FRAG(sa + aro + mi * 2048 + xc3);                              \
  }                                                                                \
  __builtin_amdgcn_s_setprio(1);                                                   \
  _Pragma("unroll") for (int q = 0; q < 2; ++q)                                    \
  _Pragma("unroll") for (int mi = 0; mi < 4; ++mi)                                 \
  _Pragma("unroll") for (int ni = 0; ni < 2; ++ni)                                 \
    acc[mi][ni] = MFMA32(a1[mi][q], b1[ni][q], acc[mi][ni]);                       \
  __builtin_amdgcn_s_setprio(0);                                                   \
  if ((VM) >= 0) {                                                                 \
    asm volatile("s_waitcnt lgkmcnt(0)" ::: "memory");                             \
    if ((VM) == 4)      asm volatile("s_waitcnt vmcnt(4)" ::: "memory");           \
    else                asm volatile("s_waitcnt vmcnt(0)" ::: "memory");           \
    __builtin_amdgcn_s_barrier();         /* END */                                \
  }                                                                                \
} while (0)

__global__ __launch_bounds__(512, 2) void gemm_bf16_fused(
    const unsigned short* __restrict__ A,
    const unsigned short* __restrict__ Bt,
    const float* __restrict__ gam, const float* __restrict__ bet,
    const float* __restrict__ mu, const float* __restrict__ var,
    float* __restrict__ C) {
  __shared__ __align__(16) unsigned short lds[65536];  // 128 KiB

  const int tid = threadIdx.x;
  const int wave = tid >> 6;
  const int lane = tid & 63;
  const int l31 = lane & 31, h5 = lane >> 5;
  const int wr = wave >> 2, wc = wave & 3;   // 2x4 wave grid; per-wave out 128x64

  // XCD-aware swizzle: 512 blocks, 512 % 8 == 0 -> bijective
  const int bid = (int)blockIdx.x;
  const int swz = (bid & 7) * 64 + (bid >> 3);
  const int bx = swz & 15;                   // 16 N-tiles
  const int by = swz >> 4;                   // 32 M-tiles
  const size_t bm = (size_t)by * 256;
  const size_t bn = (size_t)bx * 256;

  // stage source addresses (pre-swizzled global per lane; LDS dest linear)
  const int lr = lane >> 3, lc = lane & 7;
  const unsigned short* aS = A + (bm + (size_t)(wave * 8 + lr)) * K_DIM + (lc ^ lr) * 8;
  const unsigned short* bS = Bt + (bn + (size_t)(wave * 8 + lr)) * K_DIM + (lc ^ lr) * 8;

  // ds_read fragment offsets (u16 units) for 32x32x16:
  // row = l31 (row&7 == l31&7), k = kk*16 + h5*8 -> col8 = kk*2 + h5,
  // swizzled col8' = (kk*2 + h5) ^ (l31&7)
  const int xc0 = (((0 * 2 + h5) ^ (l31 & 7)) * 8);
  const int xc1 = (((1 * 2 + h5) ^ (l31 & 7)) * 8);
  const int xc2 = (((2 * 2 + h5) ^ (l31 & 7)) * 8);
  const int xc3 = (((3 * 2 + h5) ^ (l31 & 7)) * 8);
  const int aro = l31 * 64;                       // + mi*2048
  const int bro = (wc & 1) * 4096 + l31 * 64;     // + ni*2048
  const int saW = wr * 8192;
  const int sbW = 32768 + (wc >> 1) * 8192;

  f32x16 acc[4][2] = {};

  // ---- prologue: stage A(0), B(0), B(1); wait A(0)+B(0) landed ----
  STG_A(0, 0, 1, -1); STG_A(0, 1, 1, -1);
  STG_A(1, 0, 1, -1); STG_A(1, 1, 1, -1);
  asm volatile("" ::: "memory");
  STG_B(0, 0, 0, -2); STG_B(0, 1, 0, -2);
  STG_B(1, 0, 0, -2); STG_B(1, 1, 0, -2);
  asm volatile("" ::: "memory");
  STG_B(0, 0, 1, -1); STG_B(0, 1, 1, -1);
  STG_B(1, 0, 1, -1); STG_B(1, 1, 1, -1);
  asm volatile("s_waitcnt vmcnt(4)" ::: "memory");
  __builtin_amdgcn_s_barrier();

  // ---- main loop: 64 K-tiles ----
  for (int t = 0; t < 60; t += 2) {
    KTILE(t,     0, 1, 1, 4);
    KTILE(t + 1, 1, 1, 1, 4);
  }
  KTILE(60, 0, 1, 1, 4);
  KTILE(61, 1, 1, 1, 4);   // stages A(62), B(63)
  KTILE(62, 0, 1, 0, 0);   // stages A(63); drain all outstanding
  KTILE(63, 1, 0, 0, -1);  // no stages, nothing outstanding, no end barrier

  // ---- epilogue: fused BN + GELU + ReLU ----
  // 32x32 C/D layout: col = lane&31, row = (reg&3) + 8*(reg>>2) + 4*(lane>>5)
  const int row0 = (int)bm + wr * 128 + 4 * h5;
  const int col0 = (int)bn + wc * 64;
#pragma unroll
  for (int ni = 0; ni < 2; ++ni) {
    const int col = col0 + ni * 32 + l31;
    const float inv = rsqrtf(var[col] + EPS) * gam[col];
    const float shift = fmaf(-mu[col], inv, bet[col]);
#pragma unroll
    for (int mi = 0; mi < 4; ++mi) {
      const int rb = row0 + mi * 32;
#pragma unroll
      for (int q4 = 0; q4 < 4; ++q4)
#pragma unroll
        for (int r2 = 0; r2 < 4; ++r2)
          C[(size_t)(rb + q4 * 8 + r2) * N_DIM + col] =
              fused_epilogue(acc[mi][ni][q4 * 4 + r2], inv, shift);
    }
  }
}

// ---------- fallback (only if ws too small): fp32 tiled GEMM ----------

__global__ __launch_bounds__(256) void gemm_f32_fallback(
    const float* __restrict__ A, const float* __restrict__ W,
    const float* __restrict__ gam, const float* __restrict__ bet,
    const float* __restrict__ mu, const float* __restrict__ var,
    float* __restrict__ C) {
  __shared__ float As[16][65];
  __shared__ float Bs[16][65];
  const int tid = threadIdx.x;
  const int tx = tid & 15, ty = tid >> 4;
  const int bn0 = blockIdx.x * 64, bm0 = blockIdx.y * 64;
  float acc[4][4] = {};
  for (int k0 = 0; k0 < K_DIM; k0 += 16) {
#pragma unroll
    for (int j = 0; j < 4; ++j)
      As[tid & 15][(tid >> 4) * 4 + j] =
          A[(size_t)(bm0 + (tid >> 4) * 4 + j) * K_DIM + k0 + (tid & 15)];
#pragma unroll
    for (int j = 0; j < 4; ++j)
      Bs[tid >> 4][(tid & 15) * 4 + j] =
          W[(size_t)(k0 + (tid >> 4)) * N_DIM + bn0 + (tid & 15) * 4 + j];
    __syncthreads();
#pragma unroll
    for (int kk = 0; kk < 16; ++kk) {
      float a_[4], b_[4];
#pragma unroll
      for (int i = 0; i < 4; ++i) a_[i] = As[kk][ty * 4 + i];
#pragma unroll
      for (int j = 0; j < 4; ++j) b_[j] = Bs[kk][tx * 4 + j];
#pragma unroll
      for (int i = 0; i < 4; ++i)
#pragma unroll
        for (int j = 0; j < 4; ++j)
          acc[i][j] = fmaf(a_[i], b_[j], acc[i][j]);
    }
    __syncthreads();
  }
#pragma unroll
  for (int j = 0; j < 4; ++j) {
    const int col = bn0 + tx * 4 + j;
    const float inv = rsqrtf(var[col] + EPS) * gam[col];
    const float shift = fmaf(-mu[col], inv, bet[col]);
#pragma unroll
    for (int i = 0; i < 4; ++i) {
      float y = fmaf(acc[i][j], inv, shift);
      float y2 = y * y;
      float z = fmaf(0.044715f * y2, y, y);
      float e = __builtin_amdgcn_exp2f(-2.3022081f * z);
      float ge = y * __builtin_amdgcn_rcpf(1.0f + e);
      C[(size_t)(bm0 + ty * 4 + i) * N_DIM + col] = fmaxf(ge, 0.0f);
    }
  }
}

// ---------- launch ----------

extern "C" void kernel_launch(void* const* d_in, const int* in_sizes, int n_in,
                              void* d_out, int out_size, void* d_ws, size_t ws_size,
                              hipStream_t stream) {
  const float* x  = (const float*)d_in[0];
  const float* w  = (const float*)d_in[1];
  const float* gg = (const float*)d_in[2];
  const float* bb = (const float*)d_in[3];
  const float* mu = (const float*)d_in[4];
  const float* vr = (const float*)d_in[5];
  float* out = (float*)d_out;

  const size_t xb_bytes = (size_t)M_DIM * K_DIM * 2;
  const size_t wt_bytes = (size_t)K_DIM * N_DIM * 2;

  if (ws_size >= xb_bytes + wt_bytes) {
    unsigned short* xb = (unsigned short*)d_ws;
    unsigned short* wt = xb + (size_t)M_DIM * K_DIM;
    cvt_x_kernel<<<dim3((M_DIM * (size_t)K_DIM) / 8 / 256), dim3(256), 0, stream>>>(x, xb);
    cvt_w_transpose<<<dim3(N_DIM / 32, K_DIM / 32), dim3(256), 0, stream>>>(w, wt);
    gemm_bf16_fused<<<dim3((M_DIM / 256) * (N_DIM / 256)), dim3(512), 0, stream>>>(
        xb, wt, gg, bb, mu, vr, out);
  } else {
    gemm_f32_fallback<<<dim3(N_DIM / 64, M_DIM / 64), dim3(256), 0, stream>>>(
        x, w, gg, bb, mu, vr, out);
  }
}

// Round 10
// 289.649 us; speedup vs baseline: 2.2288x; 1.0596x over previous
//
#include <hip/hip_runtime.h>
#include <hip/hip_bf16.h>
#include <cstdint>
#include <cstddef>

#define M_DIM 8192
#define K_DIM 4096
#define N_DIM 4096
#define EPS 1e-5f

typedef __bf16 bf16x8 __attribute__((ext_vector_type(8)));
typedef unsigned short u16x8 __attribute__((ext_vector_type(8)));
typedef float f32x4 __attribute__((ext_vector_type(4)));

// ---------- helpers ----------

__device__ __forceinline__ unsigned short f2bf(float f) {
  unsigned int u = __builtin_bit_cast(unsigned int, f);
  u += 0x7fffu + ((u >> 16) & 1u);   // round-to-nearest-even
  return (unsigned short)(u >> 16);
}

// GELU(tanh-approx)+ReLU via identity 0.5y(1+tanh(w)) = y*sigmoid(2w):
// ge = y / (1 + exp2(-c2*z)), z = y + 0.044715 y^3, c2 = 2*0.7978845608*log2(e)
__device__ __forceinline__ float fused_epilogue(float acc, float inv, float shift) {
  float y = fmaf(acc, inv, shift);
  float y2 = y * y;
  float z = fmaf(0.044715f * y2, y, y);
  float e = __builtin_amdgcn_exp2f(-2.3022081f * z);
  float ge = y * __builtin_amdgcn_rcpf(1.0f + e);
  return fmaxf(ge, 0.0f);
}

__device__ __forceinline__ void gload_lds16(const void* gsrc, void* ldst) {
  __builtin_amdgcn_global_load_lds(
      (const __attribute__((address_space(1))) void*)gsrc,
      (__attribute__((address_space(3))) void*)ldst,
      16, 0, 0);
}

// ---------- pre-pass: fp32 -> bf16 conversions ----------

__global__ __launch_bounds__(256) void cvt_x_kernel(const float* __restrict__ x,
                                                    unsigned short* __restrict__ xb) {
  size_t i = ((size_t)blockIdx.x * 256 + threadIdx.x) * 8;
  float4 a = *reinterpret_cast<const float4*>(x + i);
  float4 b = *reinterpret_cast<const float4*>(x + i + 4);
  u16x8 o;
  o[0] = f2bf(a.x); o[1] = f2bf(a.y); o[2] = f2bf(a.z); o[3] = f2bf(a.w);
  o[4] = f2bf(b.x); o[5] = f2bf(b.y); o[6] = f2bf(b.z); o[7] = f2bf(b.w);
  *reinterpret_cast<u16x8*>(xb + i) = o;
}

// W [K][N] fp32 -> Wt [N][K] bf16 (transpose + convert)
__global__ __launch_bounds__(256) void cvt_w_transpose(const float* __restrict__ W,
                                                       unsigned short* __restrict__ Wt) {
  __shared__ float tile[32][33];
  const int tx = threadIdx.x & 31;
  const int tg = threadIdx.x >> 5;
  const int n0 = blockIdx.x * 32;
  const int k0 = blockIdx.y * 32;
#pragma unroll
  for (int j = 0; j < 4; ++j) {
    int k = tg * 4 + j;
    tile[k][tx] = W[(size_t)(k0 + k) * N_DIM + n0 + tx];
  }
  __syncthreads();
#pragma unroll
  for (int j = 0; j < 4; ++j) {
    int n = tg * 4 + j;
    Wt[(size_t)(n0 + n) * K_DIM + k0 + tx] = f2bf(tile[tx][n]);
  }
}

// ---------- main GEMM: 256x256, BK=64, 8 waves, m201-style 8-phase ----------
// 4 phases per K-tile (8 per 2-tile iteration). Per phase: {ds-reads, 1 half-tile
// stage (2 gloads), barrier, lgkm(0), setprio1, 16 MFMA, setprio0, barrier}.
// ph0 reads ALL B frags (held in regs the whole tile -> B-stage in ph2/3 is
// hazard-free) + A mi{0,1}; ph1/2/3 read A quarters. vmcnt(4) once per tile at
// ph3 (R4-proven ledger: retires A(t+1)+..., leaves newest B stages in flight).
// Addressing/swizzle/staging byte-identical to the 0-conflict R4 kernel.

#define STG_A(h, j, PAR, T)                                                        \
  gload_lds16(aS + (size_t)((h)*128 + 64*(j)) * K_DIM + (size_t)((T) + 1) * 64,    \
              &lds[(2*(1-(PAR)) + (h)) * 8192 + (wave + 8*(j)) * 512])

#define STG_B(h, j, PAR, T)                                                        \
  gload_lds16(bS + (size_t)((h)*128 + 64*(j)) * K_DIM + (size_t)((T) + 2) * 64,    \
              &lds[32768 + (2*(PAR) + (h)) * 8192 + (wave + 8*(j)) * 512])

#define LDS_FRAG(off) __builtin_bit_cast(bf16x8, *(const u16x8*)&lds[(off)])

#define RD_A(q, mi)                                                                \
  afr[q][0] = LDS_FRAG(sa + aro + (mi) * 1024 + xk0);                              \
  afr[q][1] = LDS_FRAG(sa + aro + (mi) * 1024 + xk1)

#define MF16(p)                                                                    \
  __builtin_amdgcn_s_setprio(1);                                                   \
  _Pragma("unroll") for (int kh = 0; kh < 2; ++kh)                                 \
  _Pragma("unroll") for (int q = 0; q < 2; ++q)                                    \
  _Pragma("unroll") for (int ni = 0; ni < 4; ++ni)                                 \
    acc[2*(p) + q][ni] = __builtin_amdgcn_mfma_f32_16x16x32_bf16(                  \
        afr[q][kh], bfr[ni][kh], acc[2*(p) + q][ni], 0, 0, 0);                     \
  __builtin_amdgcn_s_setprio(0)

#define BAR_IN                                                                     \
  asm volatile("" ::: "memory");                                                   \
  __builtin_amdgcn_s_barrier();                                                    \
  asm volatile("s_waitcnt lgkmcnt(0)" ::: "memory")

#define BAR_OUT                                                                    \
  asm volatile("" ::: "memory");                                                   \
  __builtin_amdgcn_s_barrier()

#define KTILE(T, PAR, STA, STB, VM) do {                                           \
  const int sa = (PAR) * 16384 + saW;                                              \
  const int sb = (PAR) * 16384 + sbW;                                              \
  bf16x8 bfr[4][2], afr[2][2];                                                     \
  /* ---- phase 0: all B + A mi{0,1}; stage A(T+1) half0 ---- */                   \
  _Pragma("unroll") for (int ni = 0; ni < 4; ++ni) {                               \
    bfr[ni][0] = LDS_FRAG(sb + bro + ni * 1024 + xk0);                             \
    bfr[ni][1] = LDS_FRAG(sb + bro + ni * 1024 + xk1);                             \
  }                                                                                \
  RD_A(0, 0); RD_A(1, 1);                                                          \
  if (STA) { STG_A(0, 0, PAR, T); STG_A(0, 1, PAR, T); }                           \
  asm volatile("s_waitcnt lgkmcnt(8)" ::: "memory");                               \
  BAR_IN;                                                                          \
  MF16(0);                                                                         \
  BAR_OUT;                                                                         \
  /* ---- phase 1: A mi{2,3}; stage A(T+1) half1 ---- */                           \
  RD_A(0, 2); RD_A(1, 3);                                                          \
  if (STA) { STG_A(1, 0, PAR, T); STG_A(1, 1, PAR, T); }                           \
  BAR_IN;                                                                          \
  MF16(1);                                                                         \
  BAR_OUT;                                                                         \
  /* ---- phase 2: A mi{4,5}; stage B(T+2) half0 ---- */                           \
  RD_A(0, 4); RD_A(1, 5);                                                          \
  if (STB) { STG_B(0, 0, PAR, T); STG_B(0, 1, PAR, T); }                           \
  BAR_IN;                                                                          \
  MF16(2);                                                                         \
  BAR_OUT;                                                                         \
  /* ---- phase 3: A mi{6,7}; stage B(T+2) half1; vmcnt at tile end ---- */        \
  RD_A(0, 6); RD_A(1, 7);                                                          \
  if (STB) { STG_B(1, 0, PAR, T); STG_B(1, 1, PAR, T); }                           \
  BAR_IN;                                                                          \
  MF16(3);                                                                         \
  if ((VM) >= 0) {                                                                 \
    if ((VM) == 4)      asm volatile("s_waitcnt vmcnt(4)" ::: "memory");           \
    else                asm volatile("s_waitcnt vmcnt(0)" ::: "memory");           \
    BAR_OUT;                                                                       \
  }                                                                                \
} while (0)

__global__ __launch_bounds__(512, 2) void gemm_bf16_fused(
    const unsigned short* __restrict__ A,
    const unsigned short* __restrict__ Bt,
    const float* __restrict__ gam, const float* __restrict__ bet,
    const float* __restrict__ mu, const float* __restrict__ var,
    float* __restrict__ C) {
  __shared__ __align__(16) unsigned short lds[65536];  // 128 KiB

  const int tid = threadIdx.x;
  const int wave = tid >> 6;
  const int lane = tid & 63;
  const int l15 = lane & 15, l4 = lane >> 4;
  const int wr = wave >> 2, wc = wave & 3;   // 2x4 wave grid; per-wave out 128x64

  // XCD-aware swizzle: 512 blocks, 512 % 8 == 0 -> bijective
  const int bid = (int)blockIdx.x;
  const int swz = (bid & 7) * 64 + (bid >> 3);
  const int bx = swz & 15;                   // 16 N-tiles
  const int by = swz >> 4;                   // 32 M-tiles
  const size_t bm = (size_t)by * 256;
  const size_t bn = (size_t)bx * 256;

  // stage source addresses (pre-swizzled global per lane; LDS dest linear)
  const int lr = lane >> 3, lc = lane & 7;
  const unsigned short* aS = A + (bm + (size_t)(wave * 8 + lr)) * K_DIM + (lc ^ lr) * 8;
  const unsigned short* bS = Bt + (bn + (size_t)(wave * 8 + lr)) * K_DIM + (lc ^ lr) * 8;

  // ds_read fragment offsets (u16 units); col8' = col8 ^ (row&7), row&7 == l15&7
  const int xk0 = ((l4)     ^ (l15 & 7)) * 8;
  const int xk1 = ((l4 | 4) ^ (l15 & 7)) * 8;
  const int aro = l15 * 64;
  const int bro = (wc & 1) * 4096 + l15 * 64;
  const int saW = wr * 8192;
  const int sbW = 32768 + (wc >> 1) * 8192;

  f32x4 acc[8][4] = {};

  // ---- prologue: stage A(0), B(0), B(1); wait A(0)+B(0) landed ----
  STG_A(0, 0, 1, -1); STG_A(0, 1, 1, -1);
  STG_A(1, 0, 1, -1); STG_A(1, 1, 1, -1);
  asm volatile("" ::: "memory");
  STG_B(0, 0, 0, -2); STG_B(0, 1, 0, -2);
  STG_B(1, 0, 0, -2); STG_B(1, 1, 0, -2);
  asm volatile("" ::: "memory");
  STG_B(0, 0, 1, -1); STG_B(0, 1, 1, -1);
  STG_B(1, 0, 1, -1); STG_B(1, 1, 1, -1);
  asm volatile("s_waitcnt vmcnt(4)" ::: "memory");
  __builtin_amdgcn_s_barrier();

  // ---- main loop: 64 K-tiles ----
  for (int t = 0; t < 60; t += 2) {
    KTILE(t,     0, 1, 1, 4);
    KTILE(t + 1, 1, 1, 1, 4);
  }
  KTILE(60, 0, 1, 1, 4);
  KTILE(61, 1, 1, 1, 4);   // stages A(62), B(63)
  KTILE(62, 0, 1, 0, 0);   // stages A(63); drain all outstanding
  KTILE(63, 1, 0, 0, -1);  // no stages, nothing outstanding, no final barrier

  // ---- epilogue: fused BN + GELU + ReLU ----
  const int row0 = (int)bm + wr * 128;
  const int col0 = (int)bn + wc * 64;
#pragma unroll
  for (int ni = 0; ni < 4; ++ni) {
    const int col = col0 + ni * 16 + l15;
    const float inv = rsqrtf(var[col] + EPS) * gam[col];
    const float shift = fmaf(-mu[col], inv, bet[col]);
#pragma unroll
    for (int mi = 0; mi < 8; ++mi) {
      const int r0 = row0 + mi * 16 + l4 * 4;
#pragma unroll
      for (int r = 0; r < 4; ++r)
        C[(size_t)(r0 + r) * N_DIM + col] = fused_epilogue(acc[mi][ni][r], inv, shift);
    }
  }
}

// ---------- fallback (only if ws too small): fp32 tiled GEMM ----------

__global__ __launch_bounds__(256) void gemm_f32_fallback(
    const float* __restrict__ A, const float* __restrict__ W,
    const float* __restrict__ gam, const float* __restrict__ bet,
    const float* __restrict__ mu, const float* __restrict__ var,
    float* __restrict__ C) {
  __shared__ float As[16][65];
  __shared__ float Bs[16][65];
  const int tid = threadIdx.x;
  const int tx = tid & 15, ty = tid >> 4;
  const int bn0 = blockIdx.x * 64, bm0 = blockIdx.y * 64;
  float acc[4][4] = {};
  for (int k0 = 0; k0 < K_DIM; k0 += 16) {
#pragma unroll
    for (int j = 0; j < 4; ++j)
      As[tid & 15][(tid >> 4) * 4 + j] =
          A[(size_t)(bm0 + (tid >> 4) * 4 + j) * K_DIM + k0 + (tid & 15)];
#pragma unroll
    for (int j = 0; j < 4; ++j)
      Bs[tid >> 4][(tid & 15) * 4 + j] =
          W[(size_t)(k0 + (tid >> 4)) * N_DIM + bn0 + (tid & 15) * 4 + j];
    __syncthreads();
#pragma unroll
    for (int kk = 0; kk < 16; ++kk) {
      float a_[4], b_[4];
#pragma unroll
      for (int i = 0; i < 4; ++i) a_[i] = As[kk][ty * 4 + i];
#pragma unroll
      for (int j = 0; j < 4; ++j) b_[j] = Bs[kk][tx * 4 + j];
#pragma unroll
      for (int i = 0; i < 4; ++i)
#pragma unroll
        for (int j = 0; j < 4; ++j)
          acc[i][j] = fmaf(a_[i], b_[j], acc[i][j]);
    }
    __syncthreads();
  }
#pragma unroll
  for (int j = 0; j < 4; ++j) {
    const int col = bn0 + tx * 4 + j;
    const float inv = rsqrtf(var[col] + EPS) * gam[col];
    const float shift = fmaf(-mu[col], inv, bet[col]);
#pragma unroll
    for (int i = 0; i < 4; ++i) {
      float y = fmaf(acc[i][j], inv, shift);
      float y2 = y * y;
      float z = fmaf(0.044715f * y2, y, y);
      float e = __builtin_amdgcn_exp2f(-2.3022081f * z);
      float ge = y * __builtin_amdgcn_rcpf(1.0f + e);
      C[(size_t)(bm0 + ty * 4 + i) * N_DIM + col] = fmaxf(ge, 0.0f);
    }
  }
}

// ---------- launch ----------

extern "C" void kernel_launch(void* const* d_in, const int* in_sizes, int n_in,
                              void* d_out, int out_size, void* d_ws, size_t ws_size,
                              hipStream_t stream) {
  const float* x  = (const float*)d_in[0];
  const float* w  = (const float*)d_in[1];
  const float* gg = (const float*)d_in[2];
  const float* bb = (const float*)d_in[3];
  const float* mu = (const float*)d_in[4];
  const float* vr = (const float*)d_in[5];
  float* out = (float*)d_out;

  const size_t xb_bytes = (size_t)M_DIM * K_DIM * 2;
  const size_t wt_bytes = (size_t)K_DIM * N_DIM * 2;

  if (ws_size >= xb_bytes + wt_bytes) {
    unsigned short* xb = (unsigned short*)d_ws;
    unsigned short* wt = xb + (size_t)M_DIM * K_DIM;
    cvt_x_kernel<<<dim3((M_DIM * (size_t)K_DIM) / 8 / 256), dim3(256), 0, stream>>>(x, xb);
    cvt_w_transpose<<<dim3(N_DIM / 32, K_DIM / 32), dim3(256), 0, stream>>>(w, wt);
    gemm_bf16_fused<<<dim3((M_DIM / 256) * (N_DIM / 256)), dim3(512), 0, stream>>>(
        xb, wt, gg, bb, mu, vr, out);
  } else {
    gemm_f32_fallback<<<dim3(N_DIM / 64, M_DIM / 64), dim3(256), 0, stream>>>(
        x, w, gg, bb, mu, vr, out);
  }
}